// Round 15
// baseline (78.755 us; speedup 1.0000x reference)
//
#include <hip/hip_runtime.h>
#include <stdint.h>

#define NR 8192
#define DD 128

typedef __attribute__((ext_vector_type(4))) int int32x4;
typedef __attribute__((ext_vector_type(8))) int int32x8;
typedef __attribute__((ext_vector_type(4))) float f32x4;

#ifdef __has_builtin
#if __has_builtin(__builtin_amdgcn_exp2f)
#define EXP2F __builtin_amdgcn_exp2f
#endif
#endif
#ifndef EXP2F
#define EXP2F exp2f
#endif

// exp(10*x) == exp2(x * 10/ln2).  10/ln2 folded into the stored values:
// q = e4m3( sqrt(10/ln2) * normalized ), so every pairwise product (MFMA
// dot, p0 elementwise, diag) is already the exp2 argument.
#define SQK 3.79828255f     // sqrt(10/ln2)
#define SCALE1 0x7F7F7F7F   // e8m0 127 = 2^0 in every byte

// ---- OCP e4m3fn software encode (RNE) / decode (exact) --------------------
__device__ __forceinline__ uint32_t enc_e4m3(float x) {
  uint32_t u = __float_as_uint(x);
  uint32_t s = (u >> 31) << 7;
  float ax = fabsf(x);
  if (ax < 0.015625f) {                 // subnormal target: m * 2^-9
    int m = (int)rintf(ax * 512.0f);    // RNE; 0..8
    return (m >= 8) ? (s | (1u << 3)) : (s | (uint32_t)m);
  }
  uint32_t v = u & 0x7FFFFFFFu;
  v += 0x7FFFFu + ((v >> 20) & 1u);     // RNE to 3 mantissa bits
  int e = (int)((v >> 23) & 255u) - 127;
  uint32_t m3 = (v >> 20) & 7u;
  return s | ((uint32_t)(e + 7) << 3) | m3;   // |x| <= ~2 -> no overflow
}
__device__ __forceinline__ float dec_e4m3(uint32_t b) {
  uint32_t s = b >> 7, e = (b >> 3) & 15u, m = b & 7u;
  float v = e ? __uint_as_float(((e + 120u) << 23) | (m << 20))
              : (float)m * 0.001953125f;      // m * 2^-9
  return s ? -v : v;
}

// ---------------------------------------------------------------------------
// K1: row L2-normalize (fp32), emit e4m3 copies scaled by SQK, diag =
// sum(dequant^2) (== the MFMA Gram diagonal).  Zeroes sums and d_out.
// ---------------------------------------------------------------------------
__global__ __launch_bounds__(256) void k_normalize(
    const float* __restrict__ u1, const float* __restrict__ u2,
    const float* __restrict__ i1, const float* __restrict__ i2,
    uint8_t* __restrict__ nb, float* __restrict__ diag,
    float* __restrict__ sums, float* __restrict__ out)
{
  int tid = threadIdx.x;
  int gid = blockIdx.x * 256 + tid;
  if (gid < 6 * NR) sums[gid] = 0.0f;
  if (gid == 0) out[0] = 0.0f;

  int w = tid >> 6, lane = tid & 63;
  int rowId = blockIdx.x * 4 + w;            // 0..32767
  int mi = rowId >> 13, r = rowId & (NR - 1);
  const float* src = (mi == 0) ? u1 : (mi == 1) ? u2 : (mi == 2) ? i1 : i2;
  const float2 v = *(const float2*)(src + (size_t)r * DD + lane * 2);
  float ss = v.x * v.x + v.y * v.y;
#pragma unroll
  for (int off = 32; off >= 1; off >>= 1) ss += __shfl_xor(ss, off, 64);
  float sc = SQK / fmaxf(sqrtf(ss), 1e-12f);
  uint32_t c0 = enc_e4m3(v.x * sc);
  uint32_t c1 = enc_e4m3(v.y * sc);
  uint8_t* dst = nb + (size_t)mi * NR * DD + (size_t)r * DD + lane * 2;
  *(uint16_t*)dst = (uint16_t)(c0 | (c1 << 8));
  float d0 = dec_e4m3(c0), d1 = dec_e4m3(c1);
  float dd = d0 * d0 + d1 * d1;
#pragma unroll
  for (int off = 32; off >= 1; off >>= 1) dd += __shfl_xor(dd, off, 64);
  if (lane == 0) diag[rowId] = dd;
}

// ---------------------------------------------------------------------------
// K2: Gram row-sums, MX-fp8 — r14 pipeline with 8 SMALL WAVES per block:
// 512 threads, MR=2 (32 rows/wave).  Rationale (r14 counters): MfmaUtil 32
// + VALUBusy 53 = 85% additive => zero overlap, because MFMA BLOCKS its
// issuing wave (within-wave overlap impossible) and only 3 waves/SIMD
// existed to cross-overlap.  8 waves halves the per-wave MFMA-blocked
// interval (2 MFMAs ~ 69cyc) and raises waves/SIMD to 4-6 (VGPR ~70 with
// MR=2), so other waves' exp/ds_read can fill the matrix-pipe shadow.
// __launch_bounds__(512,4): VGPR cap 128 >> need (r4/r12 cliff avoided);
// actual residency set by real VGPR use (<=85 -> 6 waves/SIMD).
// Everything else r14-verified: triple-buffered 8KB tiles, counted
// vmcnt(1) + raw barrier per tile, output-side exp pipeline, hoisted
// swizzled offsets.
// ---------------------------------------------------------------------------
__global__ __launch_bounds__(512, 4) void k_gram(
    const uint8_t* __restrict__ nb, float* __restrict__ sums)
{
  __shared__ alignas(16) uint8_t ldsB[3][64 * DD];   // 3 x 8 KB

  // bijective XCD-chunk swizzle: XCD k gets contiguous ids [k*96,(k+1)*96)
  int bid = (blockIdx.x & 7) * 96 + (blockIdx.x >> 3);
  int job = bid >> 7;          // 128 blocks per job
  int rem = bid & 127;
  int rb = rem >> 2;           // row-block 0..31 (256 rows each)
  int cs = rem & 3;            // col-chunk 0..3  (2048 cols each)
  const int ja[6] = {0, 0, 1, 2, 2, 3};
  const int jb[6] = {1, 0, 1, 3, 2, 3};
  const uint8_t* A = nb + (size_t)ja[job] * NR * DD;
  const uint8_t* B = nb + (size_t)jb[job] * NR * DD;
  float* out = sums + job * NR;

  int tid = threadIdx.x, w = tid >> 6, lane = tid & 63;   // w = 0..7
  int l15 = lane & 15, lg = lane >> 4;
  int rowBase = rb * 256 + w * 32;                        // 32 rows per wave

  const char* Bb = (const char*)B;
  char* ldsbase = (char*)&ldsB[0][0];
  int jstart = cs * 2048;

  // hoisted swizzled LDS byte offsets (loop-invariant)
  int offL[4], offH[4];
#pragma unroll
  for (int c = 0; c < 4; ++c) {
    int r = c * 16 + l15;
    int base = r * 128 + lg * 32;
    int swz = (r & 7) << 4;
    offL[c] = base ^ swz;
    offH[c] = (base + 16) ^ swz;
  }

  // stage one 64-col tile (8KB): 8 waves x 1KB, linear LDS dest,
  // inverse-swizzled source (rule #21).  ONE global_load_lds per wave.
#define STAGE(dst, jt)                                                        \
  {                                                                           \
    const char* tbase = Bb + (size_t)(jstart + (jt) * 64) * 128;              \
    int dbase = w * 1024;                                                     \
    int doff = dbase + lane * 16;                                             \
    int soff = doff ^ (((doff >> 7) & 7) << 4);                               \
    __builtin_amdgcn_global_load_lds(                                         \
        (const __attribute__((address_space(1))) void*)(tbase + soff),        \
        (__attribute__((address_space(3))) void*)((dst) + dbase),             \
        16, 0, 0);                                                            \
  }

  // one c-phase: 2 MFMAs for this phase, then exp/accumulate the previous
  // phase's accs (pacc0/1) — independent bursts.
#define COMPUTE(bufc)                                                         \
  {                                                                           \
    _Pragma("unroll")                                                         \
    for (int c = 0; c < 4; ++c) {                                             \
      int32x4 blo = *(const int32x4*)((bufc) + offL[c]);                      \
      int32x4 bhi = *(const int32x4*)((bufc) + offH[c]);                      \
      int32x8 b8 = __builtin_shufflevector(blo, bhi, 0, 1, 2, 3, 4, 5, 6, 7); \
      f32x4 z = {0.0f, 0.0f, 0.0f, 0.0f};                                     \
      f32x4 t0 = __builtin_amdgcn_mfma_scale_f32_16x16x128_f8f6f4(            \
          af[0], b8, z, 0, 0, 0, SCALE1, 0, SCALE1);                          \
      f32x4 t1 = __builtin_amdgcn_mfma_scale_f32_16x16x128_f8f6f4(            \
          af[1], b8, z, 0, 0, 0, SCALE1, 0, SCALE1);                          \
      _Pragma("unroll")                                                       \
      for (int j = 0; j < 4; ++j) {                                           \
        racc[0][j] += EXP2F(pacc0[j]);                                        \
        racc[1][j] += EXP2F(pacc1[j]);                                        \
      }                                                                       \
      pacc0 = t0; pacc1 = t1;                                                 \
    }                                                                         \
  }

  // prologue: stage tile 0; A-frag loads fly under it; one full drain.
  STAGE(ldsbase, 0);

  // A fragments: rows rowBase + m*16 + l15, k-bytes [lg*32, lg*32+32)
  int32x8 af[2];
#pragma unroll
  for (int m = 0; m < 2; ++m)
    af[m] = *(const int32x8*)(A + (size_t)(rowBase + m * 16 + l15) * DD + lg * 32);

  float racc[2][4];
#pragma unroll
  for (int m = 0; m < 2; ++m)
#pragma unroll
    for (int j = 0; j < 4; ++j) racc[m][j] = 0.0f;

  // output-pipeline state: exp2(-1e4) == 0.0f exactly -> first drain adds 0
  f32x4 pacc0 = {-1e4f, -1e4f, -1e4f, -1e4f};
  f32x4 pacc1 = pacc0;

  asm volatile("s_waitcnt vmcnt(0)" ::: "memory");
  __builtin_amdgcn_s_barrier();
  __builtin_amdgcn_sched_barrier(0);

  // main loop: counted-vmcnt pipeline, ONE raw barrier per tile
  int cur = 0;
  for (int jt = 0; jt < 31; ++jt) {
    int nxt = cur + 1; if (nxt == 3) nxt = 0;
    STAGE(ldsbase + nxt * 8192, jt + 1);   // 1 load issued, stays in flight
    __builtin_amdgcn_sched_barrier(0);
    asm volatile("s_waitcnt vmcnt(1)" ::: "memory");  // stage(jt) retired
    __builtin_amdgcn_s_barrier();                     // ...in ALL waves
    __builtin_amdgcn_sched_barrier(0);
    COMPUTE(ldsbase + cur * 8192);
    cur = nxt;
  }
  // epilogue: tile 31 + pipeline drain
  __builtin_amdgcn_sched_barrier(0);
  asm volatile("s_waitcnt vmcnt(0)" ::: "memory");
  __builtin_amdgcn_s_barrier();
  __builtin_amdgcn_sched_barrier(0);
  COMPUTE(ldsbase + cur * 8192);
#pragma unroll
  for (int j = 0; j < 4; ++j) {
    racc[0][j] += EXP2F(pacc0[j]);
    racc[1][j] += EXP2F(pacc1[j]);
  }

  // row-sums: reduce over the 16 lanes (cols) in each lg group
#pragma unroll
  for (int off = 1; off < 16; off <<= 1)
#pragma unroll
    for (int m = 0; m < 2; ++m)
#pragma unroll
      for (int j = 0; j < 4; ++j)
        racc[m][j] += __shfl_xor(racc[m][j], off, 64);

  if (l15 == 0) {
#pragma unroll
    for (int m = 0; m < 2; ++m)
#pragma unroll
      for (int j = 0; j < 4; ++j)
        atomicAdd(&out[rowBase + m * 16 + lg * 4 + j], racc[m][j]);
  }
#undef STAGE
#undef COMPUTE
}

// ---------------------------------------------------------------------------
// K3: finalize.  4 rows per wave-iteration (16-lane groups, 8 B/lane loads);
// 4 shuffles per row-reduce; one atomic per block (256 total).
// ---------------------------------------------------------------------------
__global__ __launch_bounds__(256) void k_finalize(
    const uint8_t* __restrict__ nb, const float* __restrict__ diag,
    const float* __restrict__ sums, float* __restrict__ out)
{
  __shared__ float part[4];
  int tid = threadIdx.x, w = tid >> 6, lane = tid & 63;
  int l15 = lane & 15, g = lane >> 4;
  int waveId = blockIdx.x * 4 + w;        // 0..1023
  float local = 0.0f;

  for (int i = 0; i < 4; ++i) {
    int rowId = waveId * 16 + i * 4 + g;  // 0..16383
    int p = rowId >> 13, r = rowId & (NR - 1);
    const uint8_t* n1 = nb + (size_t)(2 * p) * NR * DD + (size_t)r * DD + l15 * 8;
    const uint8_t* n2 = n1 + (size_t)NR * DD;
    uint2 a = *(const uint2*)n1;          // 8 e4m3 values
    uint2 b = *(const uint2*)n2;
    float p0 = 0.0f;
#pragma unroll
    for (int k = 0; k < 4; ++k)
      p0 += EXP2F(dec_e4m3((a.x >> (8 * k)) & 0xFFu) *
                  dec_e4m3((b.x >> (8 * k)) & 0xFFu));
#pragma unroll
    for (int k = 0; k < 4; ++k)
      p0 += EXP2F(dec_e4m3((a.y >> (8 * k)) & 0xFFu) *
                  dec_e4m3((b.y >> (8 * k)) & 0xFFu));
    // reduce across the 16 lanes of this group
    p0 += __shfl_xor(p0, 1, 64);
    p0 += __shfl_xor(p0, 2, 64);
    p0 += __shfl_xor(p0, 4, 64);
    p0 += __shfl_xor(p0, 8, 64);

    if (l15 == 0) {
      const float* s12v = sums + (3 * p) * NR;
      const float* s11v = sums + (3 * p + 1) * NR;
      const float* s22v = sums + (3 * p + 2) * NR;
      float e1 = EXP2F(diag[(2 * p) * NR + r]);
      float e2 = EXP2F(diag[(2 * p + 1) * NR + r]);
      float s12 = s12v[r];
      float S1 = s12 + (s11v[r] - e1) + p0;
      float S2 = s12 + (s22v[r] - e2) + p0;
      local += logf(S1) + logf(S2) - 2.0f * logf(p0);
    }
  }
  // sum the four group-leaders (other lanes hold 0)
  local += __shfl_xor(local, 16, 64);
  local += __shfl_xor(local, 32, 64);
  if (lane == 0) part[w] = local;
  __syncthreads();
  if (tid == 0) {
    float t = part[0] + part[1] + part[2] + part[3];
    atomicAdd(out, 0.25f * t);
  }
}

// ---------------------------------------------------------------------------
extern "C" void kernel_launch(void* const* d_in, const int* in_sizes, int n_in,
                              void* d_out, int out_size, void* d_ws, size_t ws_size,
                              hipStream_t stream) {
  const float* u1 = (const float*)d_in[0];
  const float* u2 = (const float*)d_in[1];
  const float* i1 = (const float*)d_in[2];
  const float* i2 = (const float*)d_in[3];

  // ws layout: 4 e4m3 matrices (4 MB) | diag[4][NR] f32 | sums[6][NR] f32
  uint8_t* nb = (uint8_t*)d_ws;
  float* diag = (float*)((char*)d_ws + (size_t)4 * NR * DD);
  float* sums = diag + 4 * NR;
  float* out = (float*)d_out;

  k_normalize<<<NR * 4 / 4, 256, 0, stream>>>(u1, u2, i1, i2, nb, diag, sums, out);
  k_gram<<<768, 512, 0, stream>>>(nb, sums);
  k_finalize<<<256, 256, 0, stream>>>(nb, diag, sums, out);
}

// Round 16
// 76.681 us; speedup vs baseline: 1.0271x; 1.0271x over previous
//
#include <hip/hip_runtime.h>
#include <stdint.h>

#define NR 8192
#define DD 128

typedef __attribute__((ext_vector_type(4))) int int32x4;
typedef __attribute__((ext_vector_type(8))) int int32x8;
typedef __attribute__((ext_vector_type(4))) float f32x4;

#ifdef __has_builtin
#if __has_builtin(__builtin_amdgcn_exp2f)
#define EXP2F __builtin_amdgcn_exp2f
#endif
#endif
#ifndef EXP2F
#define EXP2F exp2f
#endif

// exp(10*x) == exp2(x * 10/ln2).  10/ln2 folded into the stored values:
// q = e4m3( sqrt(10/ln2) * normalized ), so every pairwise product (MFMA
// dot, p0 elementwise, diag) is already the exp2 argument.
#define SQK 3.79828255f     // sqrt(10/ln2)
#define SCALE1 0x7F7F7F7F   // e8m0 127 = 2^0 in every byte

// ---- OCP e4m3fn software encode (RNE) / decode (exact) --------------------
__device__ __forceinline__ uint32_t enc_e4m3(float x) {
  uint32_t u = __float_as_uint(x);
  uint32_t s = (u >> 31) << 7;
  float ax = fabsf(x);
  if (ax < 0.015625f) {                 // subnormal target: m * 2^-9
    int m = (int)rintf(ax * 512.0f);    // RNE; 0..8
    return (m >= 8) ? (s | (1u << 3)) : (s | (uint32_t)m);
  }
  uint32_t v = u & 0x7FFFFFFFu;
  v += 0x7FFFFu + ((v >> 20) & 1u);     // RNE to 3 mantissa bits
  int e = (int)((v >> 23) & 255u) - 127;
  uint32_t m3 = (v >> 20) & 7u;
  return s | ((uint32_t)(e + 7) << 3) | m3;   // |x| <= ~2 -> no overflow
}
__device__ __forceinline__ float dec_e4m3(uint32_t b) {
  uint32_t s = b >> 7, e = (b >> 3) & 15u, m = b & 7u;
  float v = e ? __uint_as_float(((e + 120u) << 23) | (m << 20))
              : (float)m * 0.001953125f;      // m * 2^-9
  return s ? -v : v;
}

// ---------------------------------------------------------------------------
// K1: row L2-normalize (fp32), emit e4m3 copies scaled by SQK, diag =
// sum(dequant^2) (== the MFMA Gram diagonal).  Zeroes sums and d_out.
// ---------------------------------------------------------------------------
__global__ __launch_bounds__(256) void k_normalize(
    const float* __restrict__ u1, const float* __restrict__ u2,
    const float* __restrict__ i1, const float* __restrict__ i2,
    uint8_t* __restrict__ nb, float* __restrict__ diag,
    float* __restrict__ sums, float* __restrict__ out)
{
  int tid = threadIdx.x;
  int gid = blockIdx.x * 256 + tid;
  if (gid < 6 * NR) sums[gid] = 0.0f;
  if (gid == 0) out[0] = 0.0f;

  int w = tid >> 6, lane = tid & 63;
  int rowId = blockIdx.x * 4 + w;            // 0..32767
  int mi = rowId >> 13, r = rowId & (NR - 1);
  const float* src = (mi == 0) ? u1 : (mi == 1) ? u2 : (mi == 2) ? i1 : i2;
  const float2 v = *(const float2*)(src + (size_t)r * DD + lane * 2);
  float ss = v.x * v.x + v.y * v.y;
#pragma unroll
  for (int off = 32; off >= 1; off >>= 1) ss += __shfl_xor(ss, off, 64);
  float sc = SQK / fmaxf(sqrtf(ss), 1e-12f);
  uint32_t c0 = enc_e4m3(v.x * sc);
  uint32_t c1 = enc_e4m3(v.y * sc);
  uint8_t* dst = nb + (size_t)mi * NR * DD + (size_t)r * DD + lane * 2;
  *(uint16_t*)dst = (uint16_t)(c0 | (c1 << 8));
  float d0 = dec_e4m3(c0), d1 = dec_e4m3(c1);
  float dd = d0 * d0 + d1 * d1;
#pragma unroll
  for (int off = 32; off >= 1; off >>= 1) dd += __shfl_xor(dd, off, 64);
  if (lane == 0) diag[rowId] = dd;
}

// ---------------------------------------------------------------------------
// K2: Gram row-sums, MX-fp8 — r14 structure (768 blocks, 256 threads, MR=4,
// triple-buffered 8KB tiles, counted vmcnt(2) + raw barrier per tile,
// hoisted swizzled offsets) with the output pipeline recast as a
// PING-PONG register schedule:
//   phases 0/2 write paccA0..3 and exp-consume paccB0..3;
//   phases 1/3 write paccB and consume paccA.
// Register names alternate at COMPILE time -> the 16 v_mov/phase that r14's
// rotating pacc cost (~12K cyc/SIMD) vanish.  racc held as f32x4 vectors so
// the adds can emit as packed f32.  Rationale: r8-r15 showed MFMA+VALU are
// additive on a SIMD (MfmaUtil+VALUBusy pinned at ~85-88%) — runtime ==
// sum of pipe cycles, so the only lever is removing cycles.
// ---------------------------------------------------------------------------
__global__ __launch_bounds__(256, 3) void k_gram(
    const uint8_t* __restrict__ nb, float* __restrict__ sums)
{
  __shared__ alignas(16) uint8_t ldsB[3][64 * DD];   // 3 x 8 KB

  // bijective XCD-chunk swizzle: XCD k gets contiguous ids [k*96,(k+1)*96)
  int bid = (blockIdx.x & 7) * 96 + (blockIdx.x >> 3);
  int job = bid >> 7;          // 128 blocks per job
  int rem = bid & 127;
  int rb = rem >> 2;           // row-block 0..31 (256 rows each)
  int cs = rem & 3;            // col-chunk 0..3  (2048 cols each)
  const int ja[6] = {0, 0, 1, 2, 2, 3};
  const int jb[6] = {1, 0, 1, 3, 2, 3};
  const uint8_t* A = nb + (size_t)ja[job] * NR * DD;
  const uint8_t* B = nb + (size_t)jb[job] * NR * DD;
  float* out = sums + job * NR;

  int tid = threadIdx.x, w = tid >> 6, lane = tid & 63;
  int l15 = lane & 15, lg = lane >> 4;
  int rowBase = rb * 256 + w * 64;

  const char* Bb = (const char*)B;
  char* ldsbase = (char*)&ldsB[0][0];
  int jstart = cs * 2048;

  // hoisted swizzled LDS byte offsets (loop-invariant)
  int offL[4], offH[4];
#pragma unroll
  for (int c = 0; c < 4; ++c) {
    int r = c * 16 + l15;
    int base = r * 128 + lg * 32;
    int swz = (r & 7) << 4;
    offL[c] = base ^ swz;
    offH[c] = (base + 16) ^ swz;
  }

  // stage one 64-col tile (8KB): linear LDS dest, inverse-swizzled source
  // (rule #21).  2 x global_load_lds_dwordx4 per wave.
#define STAGE(dst, jt)                                                        \
  {                                                                           \
    const char* tbase = Bb + (size_t)(jstart + (jt) * 64) * 128;              \
    _Pragma("unroll")                                                         \
    for (int it = 0; it < 2; ++it) {                                          \
      int dbase = it * 4096 + w * 1024;                                       \
      int doff = dbase + lane * 16;                                           \
      int soff = doff ^ (((doff >> 7) & 7) << 4);                             \
      __builtin_amdgcn_global_load_lds(                                       \
          (const __attribute__((address_space(1))) void*)(tbase + soff),      \
          (__attribute__((address_space(3))) void*)((dst) + dbase),           \
          16, 0, 0);                                                          \
    }                                                                         \
  }

  // one c-phase: 4 MFMAs write PW*, exp/accumulate PR* (previous phase).
  // No pacc copies — the ping-pong is in the NAMES.
#define PHASE(bufc, cc, PW0, PW1, PW2, PW3, PR0, PR1, PR2, PR3)               \
  {                                                                           \
    int32x4 blo = *(const int32x4*)((bufc) + offL[cc]);                       \
    int32x4 bhi = *(const int32x4*)((bufc) + offH[cc]);                       \
    int32x8 b8 = __builtin_shufflevector(blo, bhi, 0, 1, 2, 3, 4, 5, 6, 7);   \
    f32x4 z = {0.0f, 0.0f, 0.0f, 0.0f};                                       \
    PW0 = __builtin_amdgcn_mfma_scale_f32_16x16x128_f8f6f4(                   \
        af[0], b8, z, 0, 0, 0, SCALE1, 0, SCALE1);                            \
    PW1 = __builtin_amdgcn_mfma_scale_f32_16x16x128_f8f6f4(                   \
        af[1], b8, z, 0, 0, 0, SCALE1, 0, SCALE1);                            \
    PW2 = __builtin_amdgcn_mfma_scale_f32_16x16x128_f8f6f4(                   \
        af[2], b8, z, 0, 0, 0, SCALE1, 0, SCALE1);                            \
    PW3 = __builtin_amdgcn_mfma_scale_f32_16x16x128_f8f6f4(                   \
        af[3], b8, z, 0, 0, 0, SCALE1, 0, SCALE1);                            \
    f32x4 e0, e1, e2, e3;                                                     \
    _Pragma("unroll")                                                         \
    for (int j = 0; j < 4; ++j) {                                             \
      e0[j] = EXP2F(PR0[j]); e1[j] = EXP2F(PR1[j]);                           \
      e2[j] = EXP2F(PR2[j]); e3[j] = EXP2F(PR3[j]);                           \
    }                                                                         \
    racc0 += e0; racc1 += e1; racc2 += e2; racc3 += e3;                       \
  }

  // tile = 4 phases, A/B alternating: 0:W=A,R=B  1:W=B,R=A  2:W=A,R=B
  // 3:W=B,R=A.  Tile boundary is seamless (phase 0 reads B = prior ph 3).
#define COMPUTE(bufc)                                                         \
  {                                                                           \
    PHASE(bufc, 0, pA0, pA1, pA2, pA3, pB0, pB1, pB2, pB3);                   \
    PHASE(bufc, 1, pB0, pB1, pB2, pB3, pA0, pA1, pA2, pA3);                   \
    PHASE(bufc, 2, pA0, pA1, pA2, pA3, pB0, pB1, pB2, pB3);                   \
    PHASE(bufc, 3, pB0, pB1, pB2, pB3, pA0, pA1, pA2, pA3);                   \
  }

  // prologue: stage tile 0; A-frag loads fly under it; one full drain.
  STAGE(ldsbase, 0);

  // A fragments: row rowBase+m*16+l15, k-bytes [lg*32, lg*32+32)
  int32x8 af[4];
#pragma unroll
  for (int m = 0; m < 4; ++m)
    af[m] = *(const int32x8*)(A + (size_t)(rowBase + m * 16 + l15) * DD + lg * 32);

  f32x4 racc0 = {0.0f, 0.0f, 0.0f, 0.0f};
  f32x4 racc1 = racc0, racc2 = racc0, racc3 = racc0;

  // ping-pong state: exp2(-1e4) == 0.0f exactly -> first consume adds 0
  f32x4 pB0 = {-1e4f, -1e4f, -1e4f, -1e4f};
  f32x4 pB1 = pB0, pB2 = pB0, pB3 = pB0;
  f32x4 pA0 = pB0, pA1 = pB0, pA2 = pB0, pA3 = pB0;

  asm volatile("s_waitcnt vmcnt(0)" ::: "memory");
  __builtin_amdgcn_s_barrier();
  __builtin_amdgcn_sched_barrier(0);

  // main loop: counted-vmcnt pipeline, ONE raw barrier per tile
  int cur = 0;
  for (int jt = 0; jt < 31; ++jt) {
    int nxt = cur + 1; if (nxt == 3) nxt = 0;
    STAGE(ldsbase + nxt * 8192, jt + 1);   // 2 loads issued, stay in flight
    __builtin_amdgcn_sched_barrier(0);
    asm volatile("s_waitcnt vmcnt(2)" ::: "memory");  // stage(jt) retired
    __builtin_amdgcn_s_barrier();                     // ...in ALL waves
    __builtin_amdgcn_sched_barrier(0);
    COMPUTE(ldsbase + cur * 8192);
    cur = nxt;
  }
  // epilogue: tile 31 + pipeline drain (last write was pB*)
  __builtin_amdgcn_sched_barrier(0);
  asm volatile("s_waitcnt vmcnt(0)" ::: "memory");
  __builtin_amdgcn_s_barrier();
  __builtin_amdgcn_sched_barrier(0);
  COMPUTE(ldsbase + cur * 8192);
  {
    f32x4 e0, e1, e2, e3;
#pragma unroll
    for (int j = 0; j < 4; ++j) {
      e0[j] = EXP2F(pB0[j]); e1[j] = EXP2F(pB1[j]);
      e2[j] = EXP2F(pB2[j]); e3[j] = EXP2F(pB3[j]);
    }
    racc0 += e0; racc1 += e1; racc2 += e2; racc3 += e3;
  }

  // row-sums: reduce over the 16 lanes (cols) in each lg group
#pragma unroll
  for (int off = 1; off < 16; off <<= 1)
#pragma unroll
    for (int j = 0; j < 4; ++j) {
      racc0[j] += __shfl_xor(racc0[j], off, 64);
      racc1[j] += __shfl_xor(racc1[j], off, 64);
      racc2[j] += __shfl_xor(racc2[j], off, 64);
      racc3[j] += __shfl_xor(racc3[j], off, 64);
    }

  if (l15 == 0) {
    float* outp = &out[rowBase + lg * 4];
#pragma unroll
    for (int j = 0; j < 4; ++j) {
      atomicAdd(&outp[0 * 16 + j], racc0[j]);
      atomicAdd(&outp[1 * 16 + j], racc1[j]);
      atomicAdd(&outp[2 * 16 + j], racc2[j]);
      atomicAdd(&outp[3 * 16 + j], racc3[j]);
    }
  }
#undef STAGE
#undef PHASE
#undef COMPUTE
}

// ---------------------------------------------------------------------------
// K3: finalize.  4 rows per wave-iteration (16-lane groups, 8 B/lane loads);
// 4 shuffles per row-reduce; one atomic per block (256 total).
// ---------------------------------------------------------------------------
__global__ __launch_bounds__(256) void k_finalize(
    const uint8_t* __restrict__ nb, const float* __restrict__ diag,
    const float* __restrict__ sums, float* __restrict__ out)
{
  __shared__ float part[4];
  int tid = threadIdx.x, w = tid >> 6, lane = tid & 63;
  int l15 = lane & 15, g = lane >> 4;
  int waveId = blockIdx.x * 4 + w;        // 0..1023
  float local = 0.0f;

  for (int i = 0; i < 4; ++i) {
    int rowId = waveId * 16 + i * 4 + g;  // 0..16383
    int p = rowId >> 13, r = rowId & (NR - 1);
    const uint8_t* n1 = nb + (size_t)(2 * p) * NR * DD + (size_t)r * DD + l15 * 8;
    const uint8_t* n2 = n1 + (size_t)NR * DD;
    uint2 a = *(const uint2*)n1;          // 8 e4m3 values
    uint2 b = *(const uint2*)n2;
    float p0 = 0.0f;
#pragma unroll
    for (int k = 0; k < 4; ++k)
      p0 += EXP2F(dec_e4m3((a.x >> (8 * k)) & 0xFFu) *
                  dec_e4m3((b.x >> (8 * k)) & 0xFFu));
#pragma unroll
    for (int k = 0; k < 4; ++k)
      p0 += EXP2F(dec_e4m3((a.y >> (8 * k)) & 0xFFu) *
                  dec_e4m3((b.y >> (8 * k)) & 0xFFu));
    // reduce across the 16 lanes of this group
    p0 += __shfl_xor(p0, 1, 64);
    p0 += __shfl_xor(p0, 2, 64);
    p0 += __shfl_xor(p0, 4, 64);
    p0 += __shfl_xor(p0, 8, 64);

    if (l15 == 0) {
      const float* s12v = sums + (3 * p) * NR;
      const float* s11v = sums + (3 * p + 1) * NR;
      const float* s22v = sums + (3 * p + 2) * NR;
      float e1 = EXP2F(diag[(2 * p) * NR + r]);
      float e2 = EXP2F(diag[(2 * p + 1) * NR + r]);
      float s12 = s12v[r];
      float S1 = s12 + (s11v[r] - e1) + p0;
      float S2 = s12 + (s22v[r] - e2) + p0;
      local += logf(S1) + logf(S2) - 2.0f * logf(p0);
    }
  }
  // sum the four group-leaders (other lanes hold 0)
  local += __shfl_xor(local, 16, 64);
  local += __shfl_xor(local, 32, 64);
  if (lane == 0) part[w] = local;
  __syncthreads();
  if (tid == 0) {
    float t = part[0] + part[1] + part[2] + part[3];
    atomicAdd(out, 0.25f * t);
  }
}

// ---------------------------------------------------------------------------
extern "C" void kernel_launch(void* const* d_in, const int* in_sizes, int n_in,
                              void* d_out, int out_size, void* d_ws, size_t ws_size,
                              hipStream_t stream) {
  const float* u1 = (const float*)d_in[0];
  const float* u2 = (const float*)d_in[1];
  const float* i1 = (const float*)d_in[2];
  const float* i2 = (const float*)d_in[3];

  // ws layout: 4 e4m3 matrices (4 MB) | diag[4][NR] f32 | sums[6][NR] f32
  uint8_t* nb = (uint8_t*)d_ws;
  float* diag = (float*)((char*)d_ws + (size_t)4 * NR * DD);
  float* sums = diag + 4 * NR;
  float* out = (float*)d_out;

  k_normalize<<<NR * 4 / 4, 256, 0, stream>>>(u1, u2, i1, i2, nb, diag, sums, out);
  k_gram<<<768, 256, 0, stream>>>(nb, sums);
  k_finalize<<<256, 256, 0, stream>>>(nb, diag, sums, out);
}